// Round 10
// baseline (141.333 us; speedup 1.0000x reference)
//
#include <hip/hip_runtime.h>
#include <math.h>

#define NB 16
#define NN 24
#define NA 384       /* atoms total */
#define FF 128
#define CC 27
#define MAXNBR 32    /* list capacity; physically <= 23 (image spacing L > 2r) */
#define MAXE 24      /* edges used; physical max 23 */
#define NT 20        /* gauss band terms */

// ---- static device scratch (d_ws unused). Zero at load; finishers reset their
// batch's flags each call -> clean state per graph replay.
// Sync design (R8 lineage): per-atom dataflow flags, plain st_agent stores, NO
// RMW on the sync path, no acquire/release anywhere (R1/R3: agent ACQUIRE =
// whole-L2 inv, RELEASE = whole-L2 wb -> storms). Ordering: s_waitcnt vmcnt(0)
// drains sc stores to the LLC (agent coherence point) before the flag store.
// R10: layer-0 is COMMUNICATION-FREE. feat0 = tanh(emb[z]) is computable from
// global inputs by anyone, so each block computes its neighbors' layer-0 gj/sj
// locally (+0.7us VALU) and the P0 publish + first wait round vanish: 4 hops
// -> 2 hops (P1, P2). P1 lives in projA, P2 in projB -- no buffer reuse hazard.
// Layout: 1 atom per 512-thread block, ~69KB LDS -> 2 blocks/CU co-residency
// (R9 lesson: 1 block/CU exposes every wait; co-resident blocks hide each
// other's stalls). flag[i]: 1 = P1 ready, 2 = P2 ready, 3 = feat done.
__device__ float g_sigma[4];
__device__ float g_projA[NA*4*FF];  // P1
__device__ float g_projB[NA*4*FF];  // P2
__device__ float g_feat [NA*FF];    // final feats (agent-scope)
__device__ __align__(128) int g_flag[NA][32];    // per-atom phase, own 128-B line
__device__ __align__(128) int g_sigdone[32];     // sigma blocks done (0..3)
__device__ __align__(128) int g_batchdone[32];   // finished batches (0..NB)

__device__ __forceinline__ float softplusf(float x){ return fmaxf(x,0.f) + log1pf(expf(-fabsf(x))); }
__device__ __forceinline__ float sigmoidf(float x){ return 1.f/(1.f+expf(-x)); }
__device__ __forceinline__ void st_agent(float* p, float v){
  __hip_atomic_store(p, v, __ATOMIC_RELAXED, __HIP_MEMORY_SCOPE_AGENT);
}
__device__ __forceinline__ float ld_agent(const float* p){
  return __hip_atomic_load(p, __ATOMIC_RELAXED, __HIP_MEMORY_SCOPE_AGENT);
}
__device__ __forceinline__ void st_agent_i(int* p, int v){
  __hip_atomic_store(p, v, __ATOMIC_RELAXED, __HIP_MEMORY_SCOPE_AGENT);
}
__device__ __forceinline__ int ld_agent_i(const int* p){
  return __hip_atomic_load(p, __ATOMIC_RELAXED, __HIP_MEMORY_SCOPE_AGENT);
}

// Banded Gaussian dot from PRECOMPUTED gauss table (R6-validated, bit-exact).
__device__ __forceinline__ void band_dot2(const float* __restrict__ ga, int kmin,
                                          const float* __restrict__ Wf2,
                                          const float* __restrict__ Ws2, int f,
                                          float& ge, float& se)
{
  float g = 0.f, s = 0.f;
  #pragma unroll
  for (int t = 0; t < NT; t++) {
    float a = ga[t];
    int k = kmin + t;
    g += a * Wf2[k*FF+f];
    s += a * Ws2[k*FF+f];
  }
  ge = g; se = s;
}

// per-quarter GEMV: quarter q computes one of {gi,gj,si,sj} columns
__device__ __forceinline__ float gemv_q(const float* __restrict__ Wf,
                                        const float* __restrict__ Ws,
                                        const float* s_ft, int q, int f)
{
  const float* W = (q==0) ? Wf : (q==1) ? (Wf + FF*FF) : (q==2) ? Ws : (Ws + FF*FF);
  float s = 0.f;
  #pragma unroll 16
  for (int k = 0; k < FF; k++) s += s_ft[k]*W[k*FF+f];
  return s;
}

// drain own stores to LLC, block-wide, then set this atom's phase flag.
__device__ __forceinline__ void flag_set(int i, int v)
{
  asm volatile("s_waitcnt vmcnt(0)" ::: "memory");   // own agent stores at LLC
  __syncthreads();                                    // whole block drained
  if (threadIdx.x == 0) st_agent_i(&g_flag[i][0], v);
}

// wave-0 polls neighbor flags (lane e -> neighbor e); satisfied lanes drop out.
__device__ __forceinline__ void wait_nbrs(int n, const int* s_nj, int target)
{
  if (threadIdx.x < 64) {
    int jg = (threadIdx.x < n) ? s_nj[threadIdx.x] : -1;
    bool sat = (jg < 0);
    int guard = 0;
    for (;;) {
      if (!sat) sat = (ld_agent_i(&g_flag[jg][0]) >= target);
      if (__all(sat)) break;
      __builtin_amdgcn_s_sleep(4);
      if (++guard > (1<<18)) break;   // fail visibly (absmax) instead of hanging
    }
  }
  __syncthreads();
}

// ============ single fused kernel: 3 sigma blocks + 384 atom blocks ============
// 387 blocks x 512 thr; ~69KB LDS, 64 VGPR -> 2 blocks/CU -> all resident
// (512 slots >= 387): dataflow spins cannot deadlock.
__global__ void __launch_bounds__(512, 4)
k_fused(const float* __restrict__ pos, const float* __restrict__ cell,
        const float* __restrict__ emb,
        const float* __restrict__ conv_Wf, const float* __restrict__ conv_bf,
        const float* __restrict__ conv_Ws, const float* __restrict__ conv_bs,
        const float* __restrict__ fc_W,  const float* __restrict__ fc_b,
        const float* __restrict__ W_out, const float* __restrict__ b_out,
        const int* __restrict__ z, float* __restrict__ out)
{
  const int tid = threadIdx.x;
  const int q = tid >> 7, f = tid & 127;

  // shared arrays (atom branch; sigma branch reuses sm/s_hh/s_tmp/s_red)
  __shared__ float s_ft[FF];           // running feat (residual state)
  __shared__ float s_cell[9];
  __shared__ float s_rb;
  __shared__ int   s_cnt;
  __shared__ int   s_nj[MAXNBR];       // neighbor list (global atom ids)
  __shared__ float s_nd[MAXNBR];
  __shared__ float s_nw[MAXNBR];
  __shared__ int   s_zj[MAXE];         // neighbor atomic numbers (clamped idx)
  __shared__ float s_fn[MAXE][FF];     // neighbor feat0 (R10)
  __shared__ float s_gj[MAXE][FF];     // layer-0 neighbor gj (R10, local)
  __shared__ float s_sj[MAXE][FF];     // layer-0 neighbor sj (R10, local)
  __shared__ float s_ga[MAXE][NT];     // per-edge gauss tables (R6)
  __shared__ int   s_km[MAXE];         // per-edge kmin
  __shared__ float s_ge[MAXE][FF];     // preact ge (R7)
  __shared__ float s_se[MAXE][FF];     // preact se (R7)
  __shared__ float s_p[4][FF];         // own {gi,gj,si,sj} projections
  __shared__ float sm[4][FF];          // msg quarters / GEMV partials
  __shared__ float s_hh[FF], s_tmp[FF], s_red[FF];

  if (blockIdx.x < 3) {
    // ---- spectral-norm power iteration (verbatim R8) ----
    const int m = blockIdx.x;
    const float* W = fc_W + m*FF*FF;
    if (tid < FF) s_hh[tid] = 0.08838834764831845f;     // u = 1/sqrt(128)
    __syncthreads();
    for (int it = 0; it < 5; it++) {
      { float p = 0.f;                                  // v = W u (k-split)
        #pragma unroll
        for (int k = q*32; k < q*32+32; k++) p += W[f*FF+k]*s_hh[k];
        sm[q][f] = p; }
      __syncthreads();
      if (tid < FF) { float s = sm[0][f]+sm[1][f]+sm[2][f]+sm[3][f];
                      s_tmp[f] = s; s_red[f] = s*s; }
      __syncthreads();
      for (int st=64; st>0; st>>=1){ if (tid<st) s_red[tid]+=s_red[tid+st]; __syncthreads(); }
      float nv = sqrtf(s_red[0]) + 1e-12f;
      __syncthreads();
      if (tid < FF) s_tmp[f] /= nv;
      __syncthreads();
      { float p = 0.f;                                  // u = W^T v (r-split)
        #pragma unroll
        for (int r = q*32; r < q*32+32; r++) p += W[r*FF+f]*s_tmp[r];
        sm[q][f] = p; }
      __syncthreads();
      if (tid < FF) { float s = sm[0][f]+sm[1][f]+sm[2][f]+sm[3][f];
                      s_hh[f] = s; s_red[f] = s*s; }
      __syncthreads();
      for (int st=64; st>0; st>>=1){ if (tid<st) s_red[tid]+=s_red[tid+st]; __syncthreads(); }
      float nu = sqrtf(s_red[0]) + 1e-12f;
      __syncthreads();
      if (tid < FF) s_hh[f] /= nu;
      __syncthreads();
    }
    { float p = 0.f;                                    // sigma = v . (W u)
      #pragma unroll
      for (int k = q*32; k < q*32+32; k++) p += W[f*FF+k]*s_hh[k];
      sm[q][f] = p; }
    __syncthreads();
    if (tid < FF) s_red[f] = s_tmp[f]*(sm[0][f]+sm[1][f]+sm[2][f]+sm[3][f]);
    __syncthreads();
    for (int st=64; st>0; st>>=1){ if (tid<st) s_red[tid]+=s_red[tid+st]; __syncthreads(); }
    if (tid == 0) {
      st_agent(&g_sigma[m], s_red[0]);
      asm volatile("s_waitcnt vmcnt(0)" ::: "memory");
      __hip_atomic_fetch_add(&g_sigdone[0], 1, __ATOMIC_RELAXED, __HIP_MEMORY_SCOPE_AGENT);
    }
    return;
  }

  // ---------------- atom block: whole pipeline for one atom ----------------
  const int i = (int)blockIdx.x - 3;
  const int b = i / NN;

  // ---- feat0 + cell ----
  if (tid < FF) {
    int zi = z[i]; if (zi < 1) zi = 1; if (zi > 100) zi = 100;
    s_ft[tid] = tanhf(emb[(zi-1)*FF+tid]);
  }
  if (tid >= 256 && tid < 265) s_cell[tid-256] = cell[b*9 + tid - 256];
  if (tid == 500) s_cnt = 0;
  __syncthreads();
  if (tid == 0) {
    const float* c = s_cell;
    float cx = c[4]*c[8] - c[5]*c[7];
    float cy = c[5]*c[6] - c[3]*c[8];
    float cz = c[3]*c[7] - c[4]*c[6];
    float vol = c[0]*cx + c[1]*cy + c[2]*cz;
    s_rb = cbrtf(fabsf(vol)/(float)NN);               // RADIUS_RATE = 1
  }
  __syncthreads();
  // ---- neighbor search (LDS lists; R4-lineage loop) ----
  {
    const float rb = s_rb, rb2 = rb*rb;
    const float pix = pos[i*3+0], piy = pos[i*3+1], piz = pos[i*3+2];
    const float PI = 3.14159265358979323846f;
    for (int cand = tid; cand < NN*CC; cand += 512) {
      int j = cand / CC, c = cand - j*CC;
      float gx = (float)(c/9) - 1.0f;
      float gy = (float)((c/3)%3) - 1.0f;
      float gz = (float)(c%3) - 1.0f;
      float ox = gx*s_cell[0] + gy*s_cell[3] + gz*s_cell[6];
      float oy = gx*s_cell[1] + gy*s_cell[4] + gz*s_cell[7];
      float oz = gx*s_cell[2] + gy*s_cell[5] + gz*s_cell[8];
      int jg = b*NN + j;
      float dx = pix - (pos[jg*3+0] + ox);
      float dy = piy - (pos[jg*3+1] + oy);
      float dz = piz - (pos[jg*3+2] + oz);
      float d2 = dx*dx + dy*dy + dz*dz;
      if (d2 <= rb2 && d2 > 1e-4f) {
        float dist = sqrtf(fmaxf(d2, 1e-4f));
        float w = cosf(dist*PI/rb) + 1.0f;
        int slot = atomicAdd(&s_cnt, 1);              // block-local
        if (slot < MAXNBR) { s_nj[slot] = jg; s_nd[slot] = dist; s_nw[slot] = w; }
      }
    }
  }
  __syncthreads();
  const int n0c = (s_cnt > MAXNBR) ? MAXNBR : s_cnt;
  const int n   = (n0c > MAXE) ? MAXE : n0c;           // physically <= 23

  // ---- per-edge gauss tables + neighbor z (expf bits identical; R6) ----
  if (tid < n) { int zj = z[s_nj[tid]]; if (zj < 1) zj = 1; if (zj > 100) zj = 100;
                 s_zj[tid] = zj; }
  for (int idx = tid; idx < n*NT; idx += 512) {
    int e = idx / NT, t = idx - e*NT;
    float dist = s_nd[e];
    const float step  = 6.0f/127.0f;
    const float coeff = -0.5f/(step*step);
    int kmin = (int)ceilf(dist/step - 9.0f);
    kmin = kmin < 0 ? 0 : (kmin > 108 ? 108 : kmin);
    if (t == 0) s_km[e] = kmin;
    int k = kmin + t;
    float dd = dist - step*(float)k;
    s_ga[e][t] = expf(coeff*dd*dd);
  }
  __syncthreads();

  // ---- R10: layer-0 entirely local. neighbor feat0 = tanh(emb[z_j]) ----
  for (int idx = tid; idx < n*FF; idx += 512) {
    int e = idx >> 7, k = idx & 127;
    s_fn[e][k] = tanhf(emb[(s_zj[e]-1)*FF+k]);
  }
  // own layer-0 projections (byte-identical gemv_q path)
  { float s0 = gemv_q(conv_Wf, conv_Ws, s_ft, q, f);
    s_p[q][f] = s0; }
  __syncthreads();
  // neighbor layer-0 gj/sj: same ascending-k unroll-16 chain as gemv_q, so the
  // values match what neighbor j would have published as its own gj/sj.
  {
    const float* WfJ = conv_Wf + FF*FF;     // layer-0 j-side rows
    const float* WsJ = conv_Ws + FF*FF;
    for (int idx = tid; idx < 2*n*FF; idx += 512) {
      int e = idx >> 8, h = (idx >> 7) & 1, ff = idx & 127;
      const float* W = (h == 0) ? WfJ : WsJ;
      float s = 0.f;
      #pragma unroll 16
      for (int k = 0; k < FF; k++) s += s_fn[e][k]*W[k*FF+ff];
      if (h == 0) s_gj[e][ff] = s; else s_sj[e][ff] = s;
    }
  }
  // layer-0 band preact
  {
    const float* Wf2 = conv_Wf + 2*FF*FF;
    const float* Ws2 = conv_Ws + 2*FF*FF;
    for (int idx = tid; idx < n*FF; idx += 512) {
      int e = idx >> 7, ff = idx & 127;
      float ge, se;
      band_dot2(&s_ga[e][0], s_km[e], Wf2, Ws2, ff, ge, se);
      s_ge[e][ff] = ge; s_se[e][ff] = se;
    }
  }
  __syncthreads();
  // layer-0 combine (no wait!): same accumulation order as R8 (quarter q,
  // ascending e), gj/sj substituted from LDS.
  {
    const float gi = s_p[0][f], si = s_p[2][f];
    const float bff = conv_bf[0*FF+f], bsf = conv_bs[0*FF+f];
    float msg = 0.f;
    #pragma unroll
    for (int t = 0; t < 6; ++t) {
      int e = q + 4*t;
      if (e < n)
        msg += sigmoidf(gi + s_gj[e][f] + s_ge[e][f] + bff)
             * softplusf(si + s_sj[e][f] + s_se[e][f] + bsf) * s_nw[e];
    }
    sm[q][f] = msg;
  }
  __syncthreads();
  if (tid < FF) {
    s_ft[tid] = softplusf(s_ft[tid] + sm[0][tid] + sm[1][tid]
                                    + sm[2][tid] + sm[3][tid]);
  }
  __syncthreads();
  // ---- P1 (layer-1 projections of feat1) -> publish flag 1 ----
  { float s1 = gemv_q(conv_Wf + 3*FF*FF, conv_Ws + 3*FF*FF, s_ft, q, f);
    s_p[q][f] = s1;
    st_agent(&g_projA[(i*4+q)*FF+f], s1); }
  flag_set(i, 1);

  // ---- layers 1,2: preact (hides wait) -> wait(neighbors) -> combine ----
  for (int l = 1; l < 3; ++l) {
    const float* projSrc = (l==1) ? g_projA : g_projB;
    const float* Wf2 = conv_Wf + l*3*FF*FF + 2*FF*FF;
    const float* Ws2 = conv_Ws + l*3*FF*FF + 2*FF*FF;
    for (int idx = tid; idx < n*FF; idx += 512) {
      int e = idx >> 7, ff = idx & 127;
      float ge, se;
      band_dot2(&s_ga[e][0], s_km[e], Wf2, Ws2, ff, ge, se);
      s_ge[e][ff] = ge; s_se[e][ff] = se;
    }
    __syncthreads();
    wait_nbrs(n, s_nj, l);
    // combine: prefetch 12 LLC loads back-to-back, accumulate in R8's order.
    {
      const float gi = s_p[0][f], si = s_p[2][f];
      const float bff = conv_bf[l*FF+f], bsf = conv_bs[l*FF+f];
      float gjv[6], sjv[6];
      #pragma unroll
      for (int t = 0; t < 6; ++t) {
        int e = q + 4*t;
        int jg = (e < n) ? s_nj[e] : 0;          // masked lanes read atom 0 (discarded)
        gjv[t] = ld_agent(&projSrc[(jg*4+1)*FF+f]);
        sjv[t] = ld_agent(&projSrc[(jg*4+3)*FF+f]);
      }
      float msg = 0.f;
      #pragma unroll
      for (int t = 0; t < 6; ++t) {
        int e = q + 4*t;
        if (e < n)
          msg += sigmoidf(gi + gjv[t] + s_ge[e][f] + bff)
               * softplusf(si + sjv[t] + s_se[e][f] + bsf) * s_nw[e];
      }
      sm[q][f] = msg;
    }
    __syncthreads();
    if (tid < FF) {
      s_ft[tid] = softplusf(s_ft[tid] + sm[0][tid] + sm[1][tid]
                                      + sm[2][tid] + sm[3][tid]);
    }
    __syncthreads();
    if (l == 1) {
      // P2 (layer-2 projections of feat2) -> separate buffer, flag 2
      float s2 = gemv_q(conv_Wf + 2*3*FF*FF, conv_Ws + 2*3*FF*FF, s_ft, q, f);
      s_p[q][f] = s2;
      st_agent(&g_projB[(i*4+q)*FF+f], s2);
      flag_set(i, 2);
    }
  }

  // ---- final feat ----
  if (tid < FF) st_agent(&g_feat[i*FF+tid], s_ft[tid]);
  flag_set(i, 3);
  if (i != b*NN) return;                       // only the designated finisher stays

  // ---------- designated finisher of batch b: mean + FC chain + head ----------
  if (tid < 64) {                              // wait all 24 batch flags >= 3
    int jg = (tid < NN) ? (b*NN + tid) : -1;
    bool sat = (jg < 0);
    int guard = 0;
    for (;;) {
      if (!sat) sat = (ld_agent_i(&g_flag[jg][0]) >= 3);
      if (__all(sat)) break;
      __builtin_amdgcn_s_sleep(4);
      if (++guard > (1<<18)) break;
    }
  }
  __syncthreads();
  if (tid < NN) st_agent_i(&g_flag[b*NN+tid][0], 0);   // reset batch flags (replay)
  if (tid == 0) {                              // sigma must be published
    int guard = 0;
    while (__hip_atomic_load(&g_sigdone[0], __ATOMIC_RELAXED, __HIP_MEMORY_SCOPE_AGENT) < 3) {
      __builtin_amdgcn_s_sleep(4);
      if (++guard > (1<<18)) break;
    }
  }
  __syncthreads();
  if (tid < FF) {
    float s0 = 0.f;
    for (int a = 0; a < NN; a++) s0 += ld_agent(&g_feat[(b*NN+a)*FF+tid]);
    s_hh[tid] = s0/(float)NN;
  }
  __syncthreads();
  for (int l = 0; l < 3; l++) {
    { float p = 0.f;
      #pragma unroll
      for (int k = q*32; k < q*32+32; k++) p += s_hh[k]*fc_W[l*FF*FF + k*FF + f];
      sm[q][f] = p; }
    __syncthreads();
    if (tid < FF) {
      float s = sm[0][tid]+sm[1][tid]+sm[2][tid]+sm[3][tid];
      s_tmp[tid] = softplusf(s/ld_agent(&g_sigma[l]) + fc_b[l*FF+tid]);
    }
    __syncthreads();
    if (tid < FF) s_hh[tid] = s_tmp[tid];
    __syncthreads();
  }
  if (tid < FF) s_red[tid] = s_hh[tid]*W_out[tid];
  __syncthreads();
  if (tid < 64) {
    float t = s_red[tid] + s_red[tid+64];
    #pragma unroll
    for (int off = 32; off > 0; off >>= 1) t += __shfl_xor(t, off);
    if (tid == 0) {
      out[b] = t + b_out[0];
      int d = __hip_atomic_fetch_add(&g_batchdone[0], 1, __ATOMIC_RELAXED,
                                     __HIP_MEMORY_SCOPE_AGENT);
      if (d == NB-1) {                         // globally last finisher
        __hip_atomic_store(&g_batchdone[0], 0, __ATOMIC_RELAXED, __HIP_MEMORY_SCOPE_AGENT);
        __hip_atomic_store(&g_sigdone[0],   0, __ATOMIC_RELAXED, __HIP_MEMORY_SCOPE_AGENT);
      }
    }
  }
}

extern "C" void kernel_launch(void* const* d_in, const int* in_sizes, int n_in,
                              void* d_out, int out_size, void* d_ws, size_t ws_size,
                              hipStream_t stream) {
  const float* pos     = (const float*)d_in[0];
  const float* cell    = (const float*)d_in[1];
  const float* emb     = (const float*)d_in[2];
  const float* conv_Wf = (const float*)d_in[3];
  const float* conv_bf = (const float*)d_in[4];
  const float* conv_Ws = (const float*)d_in[5];
  const float* conv_bs = (const float*)d_in[6];
  const float* fc_W    = (const float*)d_in[7];
  const float* fc_b    = (const float*)d_in[8];
  const float* W_out   = (const float*)d_in[9];
  const float* b_out   = (const float*)d_in[10];
  const int*   z       = (const int*)d_in[11];
  // d_in[12] = batch (unused); d_ws unused. All tensors fp32 (validated R3-R14).

  k_fused<<<NA+3, 512, 0, stream>>>(pos, cell, emb, conv_Wf, conv_bf,
                                    conv_Ws, conv_bs, fc_W, fc_b,
                                    W_out, b_out, z, (float*)d_out);
}

// Round 11
// 128.860 us; speedup vs baseline: 1.0968x; 1.0968x over previous
//
#include <hip/hip_runtime.h>
#include <math.h>

#define NB 16
#define NN 24
#define NA 384       /* atoms total */
#define FF 128
#define CC 27
#define MAXNBR 32    /* list capacity; physically <= 23 (image spacing L > 2r) */
#define MAXE 24      /* preact/gauss array size; >= physical max 23 */
#define NT 20        /* gauss band terms */

// ---- static device scratch (d_ws unused). Zero at load; finishers reset their
// batch's flags each call -> clean state per graph replay.
// R11 == R8 (best measured: 55us kernel / 127.6us total) + faster polls.
// Sync design: per-atom dataflow flags, plain st_agent stores, NO RMW on the
// sync path, no acquire/release anywhere (R1/R3: agent ACQUIRE = whole-L2 inv,
// RELEASE = whole-L2 wb -> device-wide storms). Ordering: s_waitcnt vmcnt(0)
// drains sc stores to the LLC (agent coherence point) before the flag store.
// flag[i] = phase of atom i (1=P0, 2=P1, 3=P2, 4=feat done).
// Buffer-reuse safety: readers of P0[i] = N(i); i overwrites P0[i] (with P2)
// only after flags(N(i))>=2, i.e. every reader finished its layer-0 combine.
// Layout: 1 atom per 512-thread block, 33KB LDS, 64 VGPR -> 2 blocks/CU
// co-residency (R9: 1/CU exposes every wait; R6/R9/R10: every consolidation
// or hop-elimination variant regressed -- this structure is the optimum).
__device__ float g_sigma[4];
__device__ float g_projA[NA*4*FF];  // P0, then P2
__device__ float g_projB[NA*4*FF];  // P1
__device__ float g_feat [NA*FF];    // final feats (agent-scope)
__device__ __align__(128) int g_flag[NA][32];    // per-atom phase, own 128-B line
__device__ __align__(128) int g_sigdone[32];     // sigma blocks done (0..3)
__device__ __align__(128) int g_batchdone[32];   // finished batches (0..NB)

__device__ __forceinline__ float softplusf(float x){ return fmaxf(x,0.f) + log1pf(expf(-fabsf(x))); }
__device__ __forceinline__ float sigmoidf(float x){ return 1.f/(1.f+expf(-x)); }
__device__ __forceinline__ void st_agent(float* p, float v){
  __hip_atomic_store(p, v, __ATOMIC_RELAXED, __HIP_MEMORY_SCOPE_AGENT);
}
__device__ __forceinline__ float ld_agent(const float* p){
  return __hip_atomic_load(p, __ATOMIC_RELAXED, __HIP_MEMORY_SCOPE_AGENT);
}
__device__ __forceinline__ void st_agent_i(int* p, int v){
  __hip_atomic_store(p, v, __ATOMIC_RELAXED, __HIP_MEMORY_SCOPE_AGENT);
}
__device__ __forceinline__ int ld_agent_i(const int* p){
  return __hip_atomic_load(p, __ATOMIC_RELAXED, __HIP_MEMORY_SCOPE_AGENT);
}

// Banded Gaussian dot from PRECOMPUTED gauss table (R6-validated, bit-exact).
__device__ __forceinline__ void band_dot2(const float* __restrict__ ga, int kmin,
                                          const float* __restrict__ Wf2,
                                          const float* __restrict__ Ws2, int f,
                                          float& ge, float& se)
{
  float g = 0.f, s = 0.f;
  #pragma unroll
  for (int t = 0; t < NT; t++) {
    float a = ga[t];
    int k = kmin + t;
    g += a * Wf2[k*FF+f];
    s += a * Ws2[k*FF+f];
  }
  ge = g; se = s;
}

// per-quarter GEMV: quarter q computes one of {gi,gj,si,sj} columns
__device__ __forceinline__ float gemv_q(const float* __restrict__ Wf,
                                        const float* __restrict__ Ws,
                                        const float* s_ft, int q, int f)
{
  const float* W = (q==0) ? Wf : (q==1) ? (Wf + FF*FF) : (q==2) ? Ws : (Ws + FF*FF);
  float s = 0.f;
  #pragma unroll 16
  for (int k = 0; k < FF; k++) s += s_ft[k]*W[k*FF+f];
  return s;
}

// drain own stores to LLC, block-wide, then set this atom's phase flag.
__device__ __forceinline__ void flag_set(int i, int v)
{
  asm volatile("s_waitcnt vmcnt(0)" ::: "memory");   // own agent stores at LLC
  __syncthreads();                                    // whole block drained
  if (threadIdx.x == 0) st_agent_i(&g_flag[i][0], v);
}

// wave-0 polls neighbor flags (lane e -> neighbor e); satisfied lanes drop out.
// s_sleep(2) ~= 128 cyc: <=23 pollers per private 128-B line stays far below
// LLC-slice limits (R3 evidence); halves detection quantization vs R8.
__device__ __forceinline__ void wait_nbrs(int n, const int* s_nj, int target)
{
  if (threadIdx.x < 64) {
    int jg = (threadIdx.x < n) ? s_nj[threadIdx.x] : -1;
    bool sat = (jg < 0);
    int guard = 0;
    for (;;) {
      if (!sat) sat = (ld_agent_i(&g_flag[jg][0]) >= target);
      if (__all(sat)) break;
      __builtin_amdgcn_s_sleep(2);
      if (++guard > (1<<19)) break;   // fail visibly (absmax) instead of hanging
    }
  }
  __syncthreads();
}

// ============ single fused kernel: 3 sigma blocks + 384 atom blocks ============
// 387 blocks x 512 thr; 33KB LDS, 64 VGPR -> 2 blocks/CU -> all resident
// (512 slots >= 387): dataflow spins cannot deadlock.
__global__ void __launch_bounds__(512, 4)
k_fused(const float* __restrict__ pos, const float* __restrict__ cell,
        const float* __restrict__ emb,
        const float* __restrict__ conv_Wf, const float* __restrict__ conv_bf,
        const float* __restrict__ conv_Ws, const float* __restrict__ conv_bs,
        const float* __restrict__ fc_W,  const float* __restrict__ fc_b,
        const float* __restrict__ W_out, const float* __restrict__ b_out,
        const int* __restrict__ z, float* __restrict__ out)
{
  const int tid = threadIdx.x;
  const int q = tid >> 7, f = tid & 127;

  // shared arrays (atom branch; sigma branch reuses sm/s_hh/s_tmp/s_red)
  __shared__ float s_ft[FF];           // running feat (residual state)
  __shared__ float s_cell[9];
  __shared__ float s_rb;
  __shared__ int   s_cnt;
  __shared__ int   s_nj[MAXNBR];       // neighbor list in LDS (global atom ids)
  __shared__ float s_nd[MAXNBR];
  __shared__ float s_nw[MAXNBR];
  __shared__ float s_ga[MAXE][NT];     // per-edge gauss tables (R6)
  __shared__ int   s_km[MAXE];         // per-edge kmin
  __shared__ float s_ge[MAXE][FF];     // preact: band_dot ge outputs (R7)
  __shared__ float s_se[MAXE][FF];     // preact: band_dot se outputs (R7)
  __shared__ float s_p[4][FF];         // own {gi,gj,si,sj} projections
  __shared__ float sm[4][FF];          // msg quarters / GEMV partials
  __shared__ float s_hh[FF], s_tmp[FF], s_red[FF];

  if (blockIdx.x < 3) {
    // ---- spectral-norm power iteration (5 iters, eps=1e-12) -- verbatim R8 ----
    const int m = blockIdx.x;
    const float* W = fc_W + m*FF*FF;
    if (tid < FF) s_hh[tid] = 0.08838834764831845f;     // u = 1/sqrt(128)
    __syncthreads();
    for (int it = 0; it < 5; it++) {
      { float p = 0.f;                                  // v = W u (k-split)
        #pragma unroll
        for (int k = q*32; k < q*32+32; k++) p += W[f*FF+k]*s_hh[k];
        sm[q][f] = p; }
      __syncthreads();
      if (tid < FF) { float s = sm[0][f]+sm[1][f]+sm[2][f]+sm[3][f];
                      s_tmp[f] = s; s_red[f] = s*s; }
      __syncthreads();
      for (int st=64; st>0; st>>=1){ if (tid<st) s_red[tid]+=s_red[tid+st]; __syncthreads(); }
      float nv = sqrtf(s_red[0]) + 1e-12f;
      __syncthreads();
      if (tid < FF) s_tmp[f] /= nv;
      __syncthreads();
      { float p = 0.f;                                  // u = W^T v (r-split)
        #pragma unroll
        for (int r = q*32; r < q*32+32; r++) p += W[r*FF+f]*s_tmp[r];
        sm[q][f] = p; }
      __syncthreads();
      if (tid < FF) { float s = sm[0][f]+sm[1][f]+sm[2][f]+sm[3][f];
                      s_hh[f] = s; s_red[f] = s*s; }
      __syncthreads();
      for (int st=64; st>0; st>>=1){ if (tid<st) s_red[tid]+=s_red[tid+st]; __syncthreads(); }
      float nu = sqrtf(s_red[0]) + 1e-12f;
      __syncthreads();
      if (tid < FF) s_hh[f] /= nu;
      __syncthreads();
    }
    { float p = 0.f;                                    // sigma = v . (W u)
      #pragma unroll
      for (int k = q*32; k < q*32+32; k++) p += W[f*FF+k]*s_hh[k];
      sm[q][f] = p; }
    __syncthreads();
    if (tid < FF) s_red[f] = s_tmp[f]*(sm[0][f]+sm[1][f]+sm[2][f]+sm[3][f]);
    __syncthreads();
    for (int st=64; st>0; st>>=1){ if (tid<st) s_red[tid]+=s_red[tid+st]; __syncthreads(); }
    if (tid == 0) {
      st_agent(&g_sigma[m], s_red[0]);
      asm volatile("s_waitcnt vmcnt(0)" ::: "memory");
      __hip_atomic_fetch_add(&g_sigdone[0], 1, __ATOMIC_RELAXED, __HIP_MEMORY_SCOPE_AGENT);
    }
    return;
  }

  // ---------------- atom block: whole pipeline for one atom ----------------
  const int i = (int)blockIdx.x - 3;
  const int b = i / NN;

  // ---- feat0 + cell ----
  if (tid < FF) {
    int zi = z[i]; if (zi < 1) zi = 1; if (zi > 100) zi = 100;
    s_ft[tid] = tanhf(emb[(zi-1)*FF+tid]);
  }
  if (tid >= 256 && tid < 265) s_cell[tid-256] = cell[b*9 + tid - 256];
  if (tid == 500) s_cnt = 0;
  __syncthreads();
  if (tid == 0) {
    const float* c = s_cell;
    float cx = c[4]*c[8] - c[5]*c[7];
    float cy = c[5]*c[6] - c[3]*c[8];
    float cz = c[3]*c[7] - c[4]*c[6];
    float vol = c[0]*cx + c[1]*cy + c[2]*cz;
    s_rb = cbrtf(fabsf(vol)/(float)NN);               // RADIUS_RATE = 1
  }
  __syncthreads();
  // ---- neighbor search (LDS lists; same loop/slot mechanism as R4-R8) ----
  {
    const float rb = s_rb, rb2 = rb*rb;
    const float pix = pos[i*3+0], piy = pos[i*3+1], piz = pos[i*3+2];
    const float PI = 3.14159265358979323846f;
    for (int cand = tid; cand < NN*CC; cand += 512) {
      int j = cand / CC, c = cand - j*CC;
      float gx = (float)(c/9) - 1.0f;
      float gy = (float)((c/3)%3) - 1.0f;
      float gz = (float)(c%3) - 1.0f;
      float ox = gx*s_cell[0] + gy*s_cell[3] + gz*s_cell[6];
      float oy = gx*s_cell[1] + gy*s_cell[4] + gz*s_cell[7];
      float oz = gx*s_cell[2] + gy*s_cell[5] + gz*s_cell[8];
      int jg = b*NN + j;
      float dx = pix - (pos[jg*3+0] + ox);
      float dy = piy - (pos[jg*3+1] + oy);
      float dz = piz - (pos[jg*3+2] + oz);
      float d2 = dx*dx + dy*dy + dz*dz;
      if (d2 <= rb2 && d2 > 1e-4f) {
        float dist = sqrtf(fmaxf(d2, 1e-4f));
        float w = cosf(dist*PI/rb) + 1.0f;
        int slot = atomicAdd(&s_cnt, 1);              // block-local
        if (slot < MAXNBR) { s_nj[slot] = jg; s_nd[slot] = dist; s_nw[slot] = w; }
      }
    }
  }
  __syncthreads();
  const int n0 = (s_cnt > MAXNBR) ? MAXNBR : s_cnt;
  const int n  = (n0 > MAXE) ? MAXE : n0;              // physically n0 <= 23

  // ---- per-edge gauss tables (expf bits identical to R4's band_dot; R6) ----
  for (int idx = tid; idx < n*NT; idx += 512) {
    int e = idx / NT, t = idx - e*NT;
    float dist = s_nd[e];
    const float step  = 6.0f/127.0f;
    const float coeff = -0.5f/(step*step);
    int kmin = (int)ceilf(dist/step - 9.0f);
    kmin = kmin < 0 ? 0 : (kmin > 108 ? 108 : kmin);
    if (t == 0) s_km[e] = kmin;
    int k = kmin + t;
    float dd = dist - step*(float)k;
    s_ga[e][t] = expf(coeff*dd*dd);
  }
  __syncthreads();

  // ---- P0 ----
  { float s0 = gemv_q(conv_Wf, conv_Ws, s_ft, q, f);
    s_p[q][f] = s0;
    st_agent(&g_projA[(i*4+q)*FF+f], s0); }
  flag_set(i, 1);

  // ---- 3 conv layers: preact (hides wait) -> wait(neighbors) -> combine ----
  for (int l = 0; l < 3; ++l) {
    const float* projSrc = (l==1) ? g_projB : g_projA;
    const float* Wf2 = conv_Wf + l*3*FF*FF + 2*FF*FF;
    const float* Ws2 = conv_Ws + l*3*FF*FF + 2*FF*FF;
    // preact: independent of other blocks -> runs while neighbor flags fill.
    for (int idx = tid; idx < n*FF; idx += 512) {
      int e = idx >> 7, ff = idx & 127;
      float ge, se;
      band_dot2(&s_ga[e][0], s_km[e], Wf2, Ws2, ff, ge, se);
      s_ge[e][ff] = ge; s_se[e][ff] = se;
    }
    __syncthreads();
    wait_nbrs(n, s_nj, l+1);
    // combine: prefetch all 12 LLC loads back-to-back (one latency exposure),
    // then accumulate in R4's exact order (quarter q, ascending e).
    {
      const float gi = s_p[0][f], si = s_p[2][f];
      const float bff = conv_bf[l*FF+f], bsf = conv_bs[l*FF+f];
      float gjv[6], sjv[6];
      #pragma unroll
      for (int t = 0; t < 6; ++t) {
        int e = q + 4*t;
        int jg = (e < n) ? s_nj[e] : 0;          // masked lanes read atom 0 (discarded)
        gjv[t] = ld_agent(&projSrc[(jg*4+1)*FF+f]);
        sjv[t] = ld_agent(&projSrc[(jg*4+3)*FF+f]);
      }
      float msg = 0.f;
      #pragma unroll
      for (int t = 0; t < 6; ++t) {
        int e = q + 4*t;
        if (e < n)
          msg += sigmoidf(gi + gjv[t] + s_ge[e][f] + bff)
               * softplusf(si + sjv[t] + s_se[e][f] + bsf) * s_nw[e];
      }
      sm[q][f] = msg;
    }
    __syncthreads();
    if (tid < FF) {
      s_ft[tid] = softplusf(s_ft[tid] + sm[0][tid] + sm[1][tid]
                                      + sm[2][tid] + sm[3][tid]);
    }
    __syncthreads();
    if (l < 2) {
      const float* WfN = conv_Wf + (l+1)*3*FF*FF;
      const float* WsN = conv_Ws + (l+1)*3*FF*FF;
      float* projDst = (l==0) ? g_projB : g_projA;  // P2 over P0: safe (header)
      float s1 = gemv_q(WfN, WsN, s_ft, q, f);
      s_p[q][f] = s1;
      st_agent(&projDst[(i*4+q)*FF+f], s1);
      flag_set(i, l+2);
    }
  }

  // ---- final feat ----
  if (tid < FF) st_agent(&g_feat[i*FF+tid], s_ft[tid]);
  flag_set(i, 4);
  if (i != b*NN) return;                       // only the designated finisher stays

  // ---------- designated finisher of batch b: mean + FC chain + head ----------
  // wait all 24 batch flags == 4 (lanes drop out as satisfied)
  if (tid < 64) {
    int jg = (tid < NN) ? (b*NN + tid) : -1;
    bool sat = (jg < 0);
    int guard = 0;
    for (;;) {
      if (!sat) sat = (ld_agent_i(&g_flag[jg][0]) >= 4);
      if (__all(sat)) break;
      __builtin_amdgcn_s_sleep(2);
      if (++guard > (1<<19)) break;
    }
  }
  __syncthreads();
  if (tid < NN) st_agent_i(&g_flag[b*NN+tid][0], 0);   // reset batch flags (replay)
  if (tid == 0) {                              // sigma must be published
    int guard = 0;
    while (__hip_atomic_load(&g_sigdone[0], __ATOMIC_RELAXED, __HIP_MEMORY_SCOPE_AGENT) < 3) {
      __builtin_amdgcn_s_sleep(2);
      if (++guard > (1<<19)) break;
    }
  }
  __syncthreads();
  if (tid < FF) {
    float s0 = 0.f;
    for (int a = 0; a < NN; a++) s0 += ld_agent(&g_feat[(b*NN+a)*FF+tid]);
    s_hh[tid] = s0/(float)NN;
  }
  __syncthreads();
  for (int l = 0; l < 3; l++) {
    { float p = 0.f;
      #pragma unroll
      for (int k = q*32; k < q*32+32; k++) p += s_hh[k]*fc_W[l*FF*FF + k*FF + f];
      sm[q][f] = p; }
    __syncthreads();
    if (tid < FF) {
      float s = sm[0][tid]+sm[1][tid]+sm[2][tid]+sm[3][tid];
      s_tmp[tid] = softplusf(s/ld_agent(&g_sigma[l]) + fc_b[l*FF+tid]);
    }
    __syncthreads();
    if (tid < FF) s_hh[tid] = s_tmp[tid];
    __syncthreads();
  }
  if (tid < FF) s_red[tid] = s_hh[tid]*W_out[tid];
  __syncthreads();
  if (tid < 64) {
    float t = s_red[tid] + s_red[tid+64];
    #pragma unroll
    for (int off = 32; off > 0; off >>= 1) t += __shfl_xor(t, off);
    if (tid == 0) {
      out[b] = t + b_out[0];
      int d = __hip_atomic_fetch_add(&g_batchdone[0], 1, __ATOMIC_RELAXED,
                                     __HIP_MEMORY_SCOPE_AGENT);
      if (d == NB-1) {                         // globally last finisher
        __hip_atomic_store(&g_batchdone[0], 0, __ATOMIC_RELAXED, __HIP_MEMORY_SCOPE_AGENT);
        __hip_atomic_store(&g_sigdone[0],   0, __ATOMIC_RELAXED, __HIP_MEMORY_SCOPE_AGENT);
      }
    }
  }
}

extern "C" void kernel_launch(void* const* d_in, const int* in_sizes, int n_in,
                              void* d_out, int out_size, void* d_ws, size_t ws_size,
                              hipStream_t stream) {
  const float* pos     = (const float*)d_in[0];
  const float* cell    = (const float*)d_in[1];
  const float* emb     = (const float*)d_in[2];
  const float* conv_Wf = (const float*)d_in[3];
  const float* conv_bf = (const float*)d_in[4];
  const float* conv_Ws = (const float*)d_in[5];
  const float* conv_bs = (const float*)d_in[6];
  const float* fc_W    = (const float*)d_in[7];
  const float* fc_b    = (const float*)d_in[8];
  const float* W_out   = (const float*)d_in[9];
  const float* b_out   = (const float*)d_in[10];
  const int*   z       = (const int*)d_in[11];
  // d_in[12] = batch (unused); d_ws unused. All tensors fp32 (validated R3-R14).

  k_fused<<<NA+3, 512, 0, stream>>>(pos, cell, emb, conv_Wf, conv_bf,
                                    conv_Ws, conv_bs, fc_W, fc_b,
                                    W_out, b_out, z, (float*)d_out);
}

// Round 12
// 128.029 us; speedup vs baseline: 1.1039x; 1.0065x over previous
//
#include <hip/hip_runtime.h>
#include <math.h>

#define NB 16
#define NN 24
#define NA 384       /* atoms total */
#define FF 128
#define CC 27
#define MAXNBR 32    /* list capacity; physically <= 23 (image spacing L > 2r) */
#define MAXE 24      /* preact/gauss array size; >= physical max 23 */
#define NT 20        /* gauss band terms */
#define NWARM 16     /* weight-warmer blocks (R12) */

// ---- static device scratch (d_ws unused). Zero at load; finishers reset their
// batch's flags each call -> clean state per graph replay.
// R12 == R11 (== R8, best measured 55.8us kernel / 127.6us total) + NWARM
// dedicated warmer blocks that stream the conv weights through each XCD's L2
// at kernel start. Rationale: the 256MiB inter-iteration fill wipes all caches;
// each layer's weights are first touched by the LEADING blocks of the dataflow
// wavefront, inside their publish chain (combine -> proj GEMV -> flag_set) --
// cold-miss latency there extends every follower's wait. Warmers front-load
// the fetch in parallel with the weight-free prologue.
// Sync design (unchanged): per-atom dataflow flags, plain st_agent stores, NO
// RMW on the sync path, no acquire/release anywhere (R1/R3: agent ACQUIRE =
// whole-L2 inv, RELEASE = whole-L2 wb -> device-wide storms). Ordering:
// s_waitcnt vmcnt(0) drains sc stores to the LLC before the flag store.
// flag[i] = phase of atom i (1=P0, 2=P1, 3=P2, 4=feat done).
// Buffer-reuse safety: readers of P0[i] = N(i); i overwrites P0[i] (with P2)
// only after flags(N(i))>=2, i.e. every reader finished its layer-0 combine.
// Layout: 1 atom per 512-thread block, 33KB LDS, 64 VGPR -> 2 blocks/CU;
// 403 blocks <= 512 resident slots -> all co-resident, spins cannot deadlock.
__device__ float g_sigma[4];
__device__ float g_projA[NA*4*FF];  // P0, then P2
__device__ float g_projB[NA*4*FF];  // P1
__device__ float g_feat [NA*FF];    // final feats (agent-scope)
__device__ __align__(128) int g_flag[NA][32];    // per-atom phase, own 128-B line
__device__ __align__(128) int g_sigdone[32];     // sigma blocks done (0..3)
__device__ __align__(128) int g_batchdone[32];   // finished batches (0..NB)

__device__ __forceinline__ float softplusf(float x){ return fmaxf(x,0.f) + log1pf(expf(-fabsf(x))); }
__device__ __forceinline__ float sigmoidf(float x){ return 1.f/(1.f+expf(-x)); }
__device__ __forceinline__ void st_agent(float* p, float v){
  __hip_atomic_store(p, v, __ATOMIC_RELAXED, __HIP_MEMORY_SCOPE_AGENT);
}
__device__ __forceinline__ float ld_agent(const float* p){
  return __hip_atomic_load(p, __ATOMIC_RELAXED, __HIP_MEMORY_SCOPE_AGENT);
}
__device__ __forceinline__ void st_agent_i(int* p, int v){
  __hip_atomic_store(p, v, __ATOMIC_RELAXED, __HIP_MEMORY_SCOPE_AGENT);
}
__device__ __forceinline__ int ld_agent_i(const int* p){
  return __hip_atomic_load(p, __ATOMIC_RELAXED, __HIP_MEMORY_SCOPE_AGENT);
}

// Banded Gaussian dot from PRECOMPUTED gauss table (R6-validated, bit-exact).
__device__ __forceinline__ void band_dot2(const float* __restrict__ ga, int kmin,
                                          const float* __restrict__ Wf2,
                                          const float* __restrict__ Ws2, int f,
                                          float& ge, float& se)
{
  float g = 0.f, s = 0.f;
  #pragma unroll
  for (int t = 0; t < NT; t++) {
    float a = ga[t];
    int k = kmin + t;
    g += a * Wf2[k*FF+f];
    s += a * Ws2[k*FF+f];
  }
  ge = g; se = s;
}

// per-quarter GEMV: quarter q computes one of {gi,gj,si,sj} columns
__device__ __forceinline__ float gemv_q(const float* __restrict__ Wf,
                                        const float* __restrict__ Ws,
                                        const float* s_ft, int q, int f)
{
  const float* W = (q==0) ? Wf : (q==1) ? (Wf + FF*FF) : (q==2) ? Ws : (Ws + FF*FF);
  float s = 0.f;
  #pragma unroll 16
  for (int k = 0; k < FF; k++) s += s_ft[k]*W[k*FF+f];
  return s;
}

// drain own stores to LLC, block-wide, then set this atom's phase flag.
__device__ __forceinline__ void flag_set(int i, int v)
{
  asm volatile("s_waitcnt vmcnt(0)" ::: "memory");   // own agent stores at LLC
  __syncthreads();                                    // whole block drained
  if (threadIdx.x == 0) st_agent_i(&g_flag[i][0], v);
}

// wave-0 polls neighbor flags (lane e -> neighbor e); satisfied lanes drop out.
__device__ __forceinline__ void wait_nbrs(int n, const int* s_nj, int target)
{
  if (threadIdx.x < 64) {
    int jg = (threadIdx.x < n) ? s_nj[threadIdx.x] : -1;
    bool sat = (jg < 0);
    int guard = 0;
    for (;;) {
      if (!sat) sat = (ld_agent_i(&g_flag[jg][0]) >= target);
      if (__all(sat)) break;
      __builtin_amdgcn_s_sleep(2);
      if (++guard > (1<<19)) break;   // fail visibly (absmax) instead of hanging
    }
  }
  __syncthreads();
}

// ==== single fused kernel: 3 sigma + 384 atom + 16 warmer blocks (403) ====
__global__ void __launch_bounds__(512, 4)
k_fused(const float* __restrict__ pos, const float* __restrict__ cell,
        const float* __restrict__ emb,
        const float* __restrict__ conv_Wf, const float* __restrict__ conv_bf,
        const float* __restrict__ conv_Ws, const float* __restrict__ conv_bs,
        const float* __restrict__ fc_W,  const float* __restrict__ fc_b,
        const float* __restrict__ W_out, const float* __restrict__ b_out,
        const int* __restrict__ z, float* __restrict__ out)
{
  const int tid = threadIdx.x;
  const int q = tid >> 7, f = tid & 127;

  if (blockIdx.x >= NA + 3) {
    // ---- R12 warmer: stream all conv weights through this XCD's L2. ----
    // No stores, no sync state -- pure cache warming; exits in a few us.
    float acc = 0.f;
    const int total4 = (3*3*FF*FF) / 4;               // per array, in float4
    const float4* pf = (const float4*)conv_Wf;
    const float4* ps = (const float4*)conv_Ws;
    for (int idx = tid; idx < total4; idx += 512) {
      float4 a = pf[idx];
      float4 c = ps[idx];
      acc += a.x + a.y + a.z + a.w + c.x + c.y + c.z + c.w;
    }
    asm volatile("" :: "v"(acc));                     // keep loads live (no DCE)
    return;
  }

  // shared arrays (atom branch; sigma branch reuses sm/s_hh/s_tmp/s_red)
  __shared__ float s_ft[FF];           // running feat (residual state)
  __shared__ float s_cell[9];
  __shared__ float s_rb;
  __shared__ int   s_cnt;
  __shared__ int   s_nj[MAXNBR];       // neighbor list in LDS (global atom ids)
  __shared__ float s_nd[MAXNBR];
  __shared__ float s_nw[MAXNBR];
  __shared__ float s_ga[MAXE][NT];     // per-edge gauss tables (R6)
  __shared__ int   s_km[MAXE];         // per-edge kmin
  __shared__ float s_ge[MAXE][FF];     // preact: band_dot ge outputs (R7)
  __shared__ float s_se[MAXE][FF];     // preact: band_dot se outputs (R7)
  __shared__ float s_p[4][FF];         // own {gi,gj,si,sj} projections
  __shared__ float sm[4][FF];          // msg quarters / GEMV partials
  __shared__ float s_hh[FF], s_tmp[FF], s_red[FF];

  if (blockIdx.x < 3) {
    // ---- spectral-norm power iteration (5 iters, eps=1e-12) -- verbatim R8 ----
    const int m = blockIdx.x;
    const float* W = fc_W + m*FF*FF;
    if (tid < FF) s_hh[tid] = 0.08838834764831845f;     // u = 1/sqrt(128)
    __syncthreads();
    for (int it = 0; it < 5; it++) {
      { float p = 0.f;                                  // v = W u (k-split)
        #pragma unroll
        for (int k = q*32; k < q*32+32; k++) p += W[f*FF+k]*s_hh[k];
        sm[q][f] = p; }
      __syncthreads();
      if (tid < FF) { float s = sm[0][f]+sm[1][f]+sm[2][f]+sm[3][f];
                      s_tmp[f] = s; s_red[f] = s*s; }
      __syncthreads();
      for (int st=64; st>0; st>>=1){ if (tid<st) s_red[tid]+=s_red[tid+st]; __syncthreads(); }
      float nv = sqrtf(s_red[0]) + 1e-12f;
      __syncthreads();
      if (tid < FF) s_tmp[f] /= nv;
      __syncthreads();
      { float p = 0.f;                                  // u = W^T v (r-split)
        #pragma unroll
        for (int r = q*32; r < q*32+32; r++) p += W[r*FF+f]*s_tmp[r];
        sm[q][f] = p; }
      __syncthreads();
      if (tid < FF) { float s = sm[0][f]+sm[1][f]+sm[2][f]+sm[3][f];
                      s_hh[f] = s; s_red[f] = s*s; }
      __syncthreads();
      for (int st=64; st>0; st>>=1){ if (tid<st) s_red[tid]+=s_red[tid+st]; __syncthreads(); }
      float nu = sqrtf(s_red[0]) + 1e-12f;
      __syncthreads();
      if (tid < FF) s_hh[f] /= nu;
      __syncthreads();
    }
    { float p = 0.f;                                    // sigma = v . (W u)
      #pragma unroll
      for (int k = q*32; k < q*32+32; k++) p += W[f*FF+k]*s_hh[k];
      sm[q][f] = p; }
    __syncthreads();
    if (tid < FF) s_red[f] = s_tmp[f]*(sm[0][f]+sm[1][f]+sm[2][f]+sm[3][f]);
    __syncthreads();
    for (int st=64; st>0; st>>=1){ if (tid<st) s_red[tid]+=s_red[tid+st]; __syncthreads(); }
    if (tid == 0) {
      st_agent(&g_sigma[m], s_red[0]);
      asm volatile("s_waitcnt vmcnt(0)" ::: "memory");
      __hip_atomic_fetch_add(&g_sigdone[0], 1, __ATOMIC_RELAXED, __HIP_MEMORY_SCOPE_AGENT);
    }
    return;
  }

  // ---------------- atom block: whole pipeline for one atom ----------------
  const int i = (int)blockIdx.x - 3;
  const int b = i / NN;

  // ---- feat0 + cell ----
  if (tid < FF) {
    int zi = z[i]; if (zi < 1) zi = 1; if (zi > 100) zi = 100;
    s_ft[tid] = tanhf(emb[(zi-1)*FF+tid]);
  }
  if (tid >= 256 && tid < 265) s_cell[tid-256] = cell[b*9 + tid - 256];
  if (tid == 500) s_cnt = 0;
  __syncthreads();
  if (tid == 0) {
    const float* c = s_cell;
    float cx = c[4]*c[8] - c[5]*c[7];
    float cy = c[5]*c[6] - c[3]*c[8];
    float cz = c[3]*c[7] - c[4]*c[6];
    float vol = c[0]*cx + c[1]*cy + c[2]*cz;
    s_rb = cbrtf(fabsf(vol)/(float)NN);               // RADIUS_RATE = 1
  }
  __syncthreads();
  // ---- neighbor search (LDS lists; same loop/slot mechanism as R4-R8) ----
  {
    const float rb = s_rb, rb2 = rb*rb;
    const float pix = pos[i*3+0], piy = pos[i*3+1], piz = pos[i*3+2];
    const float PI = 3.14159265358979323846f;
    for (int cand = tid; cand < NN*CC; cand += 512) {
      int j = cand / CC, c = cand - j*CC;
      float gx = (float)(c/9) - 1.0f;
      float gy = (float)((c/3)%3) - 1.0f;
      float gz = (float)(c%3) - 1.0f;
      float ox = gx*s_cell[0] + gy*s_cell[3] + gz*s_cell[6];
      float oy = gx*s_cell[1] + gy*s_cell[4] + gz*s_cell[7];
      float oz = gx*s_cell[2] + gy*s_cell[5] + gz*s_cell[8];
      int jg = b*NN + j;
      float dx = pix - (pos[jg*3+0] + ox);
      float dy = piy - (pos[jg*3+1] + oy);
      float dz = piz - (pos[jg*3+2] + oz);
      float d2 = dx*dx + dy*dy + dz*dz;
      if (d2 <= rb2 && d2 > 1e-4f) {
        float dist = sqrtf(fmaxf(d2, 1e-4f));
        float w = cosf(dist*PI/rb) + 1.0f;
        int slot = atomicAdd(&s_cnt, 1);              // block-local
        if (slot < MAXNBR) { s_nj[slot] = jg; s_nd[slot] = dist; s_nw[slot] = w; }
      }
    }
  }
  __syncthreads();
  const int n0 = (s_cnt > MAXNBR) ? MAXNBR : s_cnt;
  const int n  = (n0 > MAXE) ? MAXE : n0;              // physically n0 <= 23

  // ---- per-edge gauss tables (expf bits identical to R4's band_dot; R6) ----
  for (int idx = tid; idx < n*NT; idx += 512) {
    int e = idx / NT, t = idx - e*NT;
    float dist = s_nd[e];
    const float step  = 6.0f/127.0f;
    const float coeff = -0.5f/(step*step);
    int kmin = (int)ceilf(dist/step - 9.0f);
    kmin = kmin < 0 ? 0 : (kmin > 108 ? 108 : kmin);
    if (t == 0) s_km[e] = kmin;
    int k = kmin + t;
    float dd = dist - step*(float)k;
    s_ga[e][t] = expf(coeff*dd*dd);
  }
  __syncthreads();

  // ---- P0 ----
  { float s0 = gemv_q(conv_Wf, conv_Ws, s_ft, q, f);
    s_p[q][f] = s0;
    st_agent(&g_projA[(i*4+q)*FF+f], s0); }
  flag_set(i, 1);

  // ---- 3 conv layers: preact (hides wait) -> wait(neighbors) -> combine ----
  for (int l = 0; l < 3; ++l) {
    const float* projSrc = (l==1) ? g_projB : g_projA;
    const float* Wf2 = conv_Wf + l*3*FF*FF + 2*FF*FF;
    const float* Ws2 = conv_Ws + l*3*FF*FF + 2*FF*FF;
    // preact: independent of other blocks -> runs while neighbor flags fill.
    for (int idx = tid; idx < n*FF; idx += 512) {
      int e = idx >> 7, ff = idx & 127;
      float ge, se;
      band_dot2(&s_ga[e][0], s_km[e], Wf2, Ws2, ff, ge, se);
      s_ge[e][ff] = ge; s_se[e][ff] = se;
    }
    __syncthreads();
    wait_nbrs(n, s_nj, l+1);
    // combine: prefetch all 12 LLC loads back-to-back (one latency exposure),
    // then accumulate in R4's exact order (quarter q, ascending e).
    {
      const float gi = s_p[0][f], si = s_p[2][f];
      const float bff = conv_bf[l*FF+f], bsf = conv_bs[l*FF+f];
      float gjv[6], sjv[6];
      #pragma unroll
      for (int t = 0; t < 6; ++t) {
        int e = q + 4*t;
        int jg = (e < n) ? s_nj[e] : 0;          // masked lanes read atom 0 (discarded)
        gjv[t] = ld_agent(&projSrc[(jg*4+1)*FF+f]);
        sjv[t] = ld_agent(&projSrc[(jg*4+3)*FF+f]);
      }
      float msg = 0.f;
      #pragma unroll
      for (int t = 0; t < 6; ++t) {
        int e = q + 4*t;
        if (e < n)
          msg += sigmoidf(gi + gjv[t] + s_ge[e][f] + bff)
               * softplusf(si + sjv[t] + s_se[e][f] + bsf) * s_nw[e];
      }
      sm[q][f] = msg;
    }
    __syncthreads();
    if (tid < FF) {
      s_ft[tid] = softplusf(s_ft[tid] + sm[0][tid] + sm[1][tid]
                                      + sm[2][tid] + sm[3][tid]);
    }
    __syncthreads();
    if (l < 2) {
      const float* WfN = conv_Wf + (l+1)*3*FF*FF;
      const float* WsN = conv_Ws + (l+1)*3*FF*FF;
      float* projDst = (l==0) ? g_projB : g_projA;  // P2 over P0: safe (header)
      float s1 = gemv_q(WfN, WsN, s_ft, q, f);
      s_p[q][f] = s1;
      st_agent(&projDst[(i*4+q)*FF+f], s1);
      flag_set(i, l+2);
    }
  }

  // ---- final feat ----
  if (tid < FF) st_agent(&g_feat[i*FF+tid], s_ft[tid]);
  flag_set(i, 4);
  if (i != b*NN) return;                       // only the designated finisher stays

  // ---------- designated finisher of batch b: mean + FC chain + head ----------
  // wait all 24 batch flags == 4 (lanes drop out as satisfied)
  if (tid < 64) {
    int jg = (tid < NN) ? (b*NN + tid) : -1;
    bool sat = (jg < 0);
    int guard = 0;
    for (;;) {
      if (!sat) sat = (ld_agent_i(&g_flag[jg][0]) >= 4);
      if (__all(sat)) break;
      __builtin_amdgcn_s_sleep(2);
      if (++guard > (1<<19)) break;
    }
  }
  __syncthreads();
  if (tid < NN) st_agent_i(&g_flag[b*NN+tid][0], 0);   // reset batch flags (replay)
  if (tid == 0) {                              // sigma must be published
    int guard = 0;
    while (__hip_atomic_load(&g_sigdone[0], __ATOMIC_RELAXED, __HIP_MEMORY_SCOPE_AGENT) < 3) {
      __builtin_amdgcn_s_sleep(2);
      if (++guard > (1<<19)) break;
    }
  }
  __syncthreads();
  if (tid < FF) {
    float s0 = 0.f;
    for (int a = 0; a < NN; a++) s0 += ld_agent(&g_feat[(b*NN+a)*FF+tid]);
    s_hh[tid] = s0/(float)NN;
  }
  __syncthreads();
  for (int l = 0; l < 3; l++) {
    { float p = 0.f;
      #pragma unroll
      for (int k = q*32; k < q*32+32; k++) p += s_hh[k]*fc_W[l*FF*FF + k*FF + f];
      sm[q][f] = p; }
    __syncthreads();
    if (tid < FF) {
      float s = sm[0][tid]+sm[1][tid]+sm[2][tid]+sm[3][tid];
      s_tmp[tid] = softplusf(s/ld_agent(&g_sigma[l]) + fc_b[l*FF+tid]);
    }
    __syncthreads();
    if (tid < FF) s_hh[tid] = s_tmp[tid];
    __syncthreads();
  }
  if (tid < FF) s_red[tid] = s_hh[tid]*W_out[tid];
  __syncthreads();
  if (tid < 64) {
    float t = s_red[tid] + s_red[tid+64];
    #pragma unroll
    for (int off = 32; off > 0; off >>= 1) t += __shfl_xor(t, off);
    if (tid == 0) {
      out[b] = t + b_out[0];
      int d = __hip_atomic_fetch_add(&g_batchdone[0], 1, __ATOMIC_RELAXED,
                                     __HIP_MEMORY_SCOPE_AGENT);
      if (d == NB-1) {                         // globally last finisher
        __hip_atomic_store(&g_batchdone[0], 0, __ATOMIC_RELAXED, __HIP_MEMORY_SCOPE_AGENT);
        __hip_atomic_store(&g_sigdone[0],   0, __ATOMIC_RELAXED, __HIP_MEMORY_SCOPE_AGENT);
      }
    }
  }
}

extern "C" void kernel_launch(void* const* d_in, const int* in_sizes, int n_in,
                              void* d_out, int out_size, void* d_ws, size_t ws_size,
                              hipStream_t stream) {
  const float* pos     = (const float*)d_in[0];
  const float* cell    = (const float*)d_in[1];
  const float* emb     = (const float*)d_in[2];
  const float* conv_Wf = (const float*)d_in[3];
  const float* conv_bf = (const float*)d_in[4];
  const float* conv_Ws = (const float*)d_in[5];
  const float* conv_bs = (const float*)d_in[6];
  const float* fc_W    = (const float*)d_in[7];
  const float* fc_b    = (const float*)d_in[8];
  const float* W_out   = (const float*)d_in[9];
  const float* b_out   = (const float*)d_in[10];
  const int*   z       = (const int*)d_in[11];
  // d_in[12] = batch (unused); d_ws unused. All tensors fp32 (validated R3-R14).

  k_fused<<<NA+3+NWARM, 512, 0, stream>>>(pos, cell, emb, conv_Wf, conv_bf,
                                          conv_Ws, conv_bs, fc_W, fc_b,
                                          W_out, b_out, z, (float*)d_out);
}